// Round 9
// baseline (335.787 us; speedup 1.0000x reference)
//
#include <hip/hip_runtime.h>

// TemporalLogicLayer R9: single fused persistent kernel (prep + main + finalize).
// out[b,t,o] = max_{s>=t} sigmoid(5*(relu(relu([cummax(P[t..s])|P[s]]W1+b1)W2+b2)W3+b3))
//
// R8 post-mortem: main 149 us but total 220 us — ~71 us is prep/finalize
// launch+serialization overhead (constant ~70 us since R5). R9 fuses all
// phases into one 512-block kernel (512 = exact 2-blocks/CU capacity ->
// co-residency guaranteed -> counter-based grid barriers are safe):
//   phase1: W transpose (W1 full [144][256]) + Pf f16 convert (all 512 blocks)
//   barrier; phase2: PW = Pf @ W1[128:] via MFMA, contiguous W1tF loads
//   (blocks < 256); barrier; main loop (identical to R8); flush writes slots
//   with plain stores + device fence + per-t arrival counter; LAST arriver
//   finalizes that t inline (max over slots, sigmoid, write out).
// Counters zeroed by one hipMemsetAsync. Launches: 1 memset + 1 kernel.

#define TT 128
#define BB 32
#define DD 128
#define OO 64
#define NP 144
#define HSTR 168
#define KSLOT 9
#define NBLK 512

typedef __attribute__((ext_vector_type(8))) _Float16 half8;
typedef __attribute__((ext_vector_type(4))) _Float16 half4;
typedef __attribute__((ext_vector_type(4))) float f32x4;

// ws layout (bytes)
#define W1T_OFF 0                                   // f16 [144][256] FULL transpose
#define W2T_OFF (W1T_OFF + 144*256*2)               // f16 [144][160]
#define W3T_OFF (W2T_OFF + 144*160*2)               // f16 [64][160]
#define B1P_OFF (W3T_OFF + 64*160*2)                // f32 [144]
#define B2P_OFF (B1P_OFF + 144*4)                   // f32 [144]
#define PW_OFF  (B2P_OFF + 144*4)                   // f16 [4096][144]
#define PF_OFF  (PW_OFF + 4096*144*2)               // f16 [32][128][128]
#define SLOT_OFF (PF_OFF + 32*128*128*2)            // f16 [128][KSLOT][32][64]
#define CTR_OFF  (SLOT_OFF + 128*KSLOT*2048*2)      // u32 tctr[128] + gctr[2]

#define MFMA(A, B, C) __builtin_amdgcn_mfma_f32_16x16x32_f16((A), (B), (C), 0, 0, 0)

__device__ __forceinline__ half8 h8max(half8 a, half8 b) {
    half8 r;
    #pragma unroll
    for (int i = 0; i < 8; ++i) r[i] = (a[i] > b[i]) ? a[i] : b[i];
    return r;
}

// largest bid with range_start(bid) = (bid*33)>>3 <= it   (512-block partition)
__device__ __forceinline__ int bid_of(int it) {
    int bb = (8 * it) / 33;
    while ((((bb + 1) * 33) >> 3) <= it) ++bb;
    while (((bb * 33) >> 3) > it) --bb;
    return bb;
}

// grid barrier: all NBLK blocks co-resident (512 = exact capacity at 75776 B
// LDS, 512 thr, <=128 VGPR) -> spin is deadlock-free. Release/acquire via
// __threadfence (agent-scope wbl2/inv).
__device__ __forceinline__ void gridbar(unsigned* ctr, unsigned target, int tid) {
    __syncthreads();                   // drains this block's vmem (compiler waitcnt)
    if (tid == 0) {
        __threadfence();               // release: write back L2
        atomicAdd(ctr, 1u);
        while (atomicAdd(ctr, 0u) < target) __builtin_amdgcn_s_sleep(2);
        __threadfence();               // acquire: invalidate L1/L2
    }
    __syncthreads();
}

__global__ __launch_bounds__(512, 4) void tll_fused(
    const float* __restrict__ P,
    const float* __restrict__ W1, const float* __restrict__ b1,
    const float* __restrict__ W2, const float* __restrict__ b2,
    const float* __restrict__ W3, const float* __restrict__ b3,
    char* __restrict__ ws, float* __restrict__ out)
{
    extern __shared__ char smem[];
    _Float16* hS  = (_Float16*)smem;                // [128][168] = 43008 B
    _Float16* cmx = hS + 128*HSTR;                  // [128][128] swizzled, 32768 B

    _Float16* W1tF = (_Float16*)(ws + W1T_OFF);
    _Float16* W2t  = (_Float16*)(ws + W2T_OFF);
    _Float16* W3t  = (_Float16*)(ws + W3T_OFF);
    float*    b1p  = (float*)(ws + B1P_OFF);
    float*    b2p  = (float*)(ws + B2P_OFF);
    _Float16* PW   = (_Float16*)(ws + PW_OFF);
    _Float16* Pf   = (_Float16*)(ws + PF_OFF);
    _Float16* slots = (_Float16*)(ws + SLOT_OFF);
    unsigned* tctr = (unsigned*)(ws + CTR_OFF);
    unsigned* gctr = tctr + 128;

    const int tid = threadIdx.x, bid = blockIdx.x;
    const int w = tid >> 6, lane = tid & 63;
    const int ln = lane & 15, q = lane >> 4;

    // ================= phase 1: W transpose + Pf convert =================
    {
        int gid = bid * 512 + tid;                  // 262144 threads
        if (gid < 144*256) {                        // W1tF[n][k] = W1[k][n]
            int n = gid >> 8, k = gid & 255;
            W1tF[gid] = (_Float16)((n < 132) ? W1[k*132 + n] : 0.f);
        }
        if (gid < 144*160) {                        // W2t[n][k] = W2[k][n]
            int n = gid / 160, k = gid - n*160;
            W2t[gid] = (_Float16)((n < 132 && k < 132) ? W2[k*132 + n] : 0.f);
        }
        if (gid < 64*160) {                         // W3t[o][k] = W3[k][o]
            int o = gid / 160, k = gid - o*160;
            W3t[gid] = (_Float16)((k < 132) ? W3[k*64 + o] : 0.f);
        }
        if (gid < 144) {
            b1p[gid] = (gid < 132) ? b1[gid] : 0.f;
            b2p[gid] = (gid < 132) ? b2[gid] : 0.f;
        }
        if (gid < 131072) {                         // Pf = f16(P), flat f32x4->half4
            f32x4 v = ((const f32x4*)P)[gid];
            half4 h;
            #pragma unroll
            for (int j = 0; j < 4; ++j) h[j] = (_Float16)v[j];
            ((half4*)Pf)[gid] = h;
        }
    }
    gridbar(&gctr[0], NBLK, tid);

    // ================= phase 2: PW = Pf @ W1[128:256,:] =================
    if (bid < 256) {
        const int rt = bid;                          // row-tile: rows rt*16..+15
        const int row = rt*16 + ln;                  // row = s*32 + b
        const int b_ = row & 31, s_ = row >> 5;
        const _Float16* pp = Pf + (size_t)b_*(TT*DD) + s_*DD;
        half8 Bf[4];
        #pragma unroll
        for (int kst = 0; kst < 4; ++kst)
            Bf[kst] = *(const half8*)(pp + kst*32 + q*8);
        const int nmt = (w == 0) ? 2 : 1;            // wave w -> mt=w (+ mt=8 for w0)
        for (int im = 0; im < nmt; ++im) {
            int mt = (im == 0) ? w : 8;
            f32x4 acc = (f32x4){0.f, 0.f, 0.f, 0.f};
            #pragma unroll
            for (int kst = 0; kst < 4; ++kst) {
                half8 A = *(const half8*)(W1tF + (mt*16 + ln)*256 + 128 + kst*32 + q*8);
                acc = MFMA(A, Bf[kst], acc);
            }
            half4 hv;
            #pragma unroll
            for (int i = 0; i < 4; ++i) hv[i] = (_Float16)acc[i];
            *(half4*)(PW + (size_t)row*NP + mt*16 + q*4) = hv;
        }
    }
    gridbar(&gctr[1], NBLK, tid);

    // ================= main =================
    const int fg = w >> 1, rg = w & 1;              // 4 f-groups x 2 r-groups
    const bool has3 = (fg == 0);                    // f-tiles (3,2,2,2) of 9
    const int fb = (fg == 0) ? 0 : (16 + 32*fg);    // 0,48,80,112
    const int f0A = fb, f0B = fb + 16, f0C = fb + 32;
    const int og = fg, rg3 = rg;                    // L3: o-tile, j-group

    // zero hS cols 144..159 (K padding read by L2'/L3'; avoid NaN garbage)
    for (int idx = tid; idx < 256; idx += 512) {
        int row = idx >> 1, hv = idx & 1;
        half8 z;
        #pragma unroll
        for (int i = 0; i < 8; ++i) z[i] = (_Float16)0.f;
        *(half8*)(hS + row*HSTR + 144 + hv*8) = z;
    }

    const int sb = tid >> 4, dblk = tid & 15, d0 = dblk*8;  // staging role
    const _Float16* pfb = Pf + (size_t)sb*(TT*DD) + d0;

    int it = (bid*33) >> 3;                          // contiguous t-major ranges
    const int hi = ((bid + 1)*33) >> 3;

    int cur_t = -1;
    f32x4 rz0 = (f32x4){-1e30f,-1e30f,-1e30f,-1e30f};  // z-domain max, b=ln
    f32x4 rz1 = rz0;                                    // b=16+ln
    half8 mi;                                           // carried cummax Pf[b,t..s0-1,d]
    __syncthreads();

    // flush z-max -> slot; last arriver finalizes t (split-K fixup pattern)
    auto flush_t = [&](int ct) {
        float* scr = (float*)cmx;                    // cmx dead at flush points
        if (rg3 == 1) {
            *(f32x4*)(scr + (og*64 + lane)*8)     = rz0;
            *(f32x4*)(scr + (og*64 + lane)*8 + 4) = rz1;
        }
        __syncthreads();
        int g2 = ct >> 2;
        int it_s = 2*g2*(65 - g2) + (ct - 4*g2)*(32 - g2);
        if (rg3 == 0) {
            f32x4 p0 = *(const f32x4*)(scr + (og*64 + lane)*8);
            f32x4 p1 = *(const f32x4*)(scr + (og*64 + lane)*8 + 4);
            #pragma unroll
            for (int i = 0; i < 4; ++i) {
                rz0[i] = fmaxf(rz0[i], p0[i]);
                rz1[i] = fmaxf(rz1[i], p1[i]);
            }
            int k = bid - bid_of(it_s);
            _Float16* sp = slots + ((size_t)ct*KSLOT + k)*2048;
            int o = og*16 + q*4;
            half4 z0, z1;
            #pragma unroll
            for (int i = 0; i < 4; ++i) { z0[i] = (_Float16)rz0[i]; z1[i] = (_Float16)rz1[i]; }
            *(half4*)(sp + ln*64 + o) = z0;
            *(half4*)(sp + (16+ln)*64 + o) = z1;
        }
        __syncthreads();                             // slot stores drained (vmcnt)
        if (tid == 0) {
            __threadfence();                         // release: wbl2
            int it_e = it_s + (32 - g2);
            int nT = bid_of(it_e - 1) - bid_of(it_s) + 1;
            unsigned r = atomicAdd(&tctr[ct], 1u);
            unsigned win = (r == (unsigned)(nT - 1)) ? 1u : 0u;
            if (win) __threadfence();                // acquire: inv L1/L2
            ((volatile unsigned*)scr)[0] = win;
            ((volatile int*)scr)[1] = nT;
        }
        __syncthreads();
        if (((volatile unsigned*)scr)[0]) {          // this block finalizes t=ct
            int nT = ((volatile int*)scr)[1];
            const _Float16* sb2 = slots + (size_t)ct*KSLOT*2048;
            int cell = tid * 4;                      // b*64+o
            half4 h = *(const half4*)(sb2 + cell);
            f32x4 v;
            #pragma unroll
            for (int i = 0; i < 4; ++i) v[i] = (float)h[i];
            for (int k2 = 1; k2 < nT; ++k2) {
                half4 u = *(const half4*)(sb2 + k2*2048 + cell);
                #pragma unroll
                for (int i = 0; i < 4; ++i) v[i] = fmaxf(v[i], (float)u[i]);
            }
            f32x4 y;
            #pragma unroll
            for (int i = 0; i < 4; ++i) y[i] = 1.f / (1.f + __expf(-5.f * v[i]));
            *(f32x4*)(out + (size_t)(cell >> 6)*(TT*OO) + ct*OO + (cell & 63)) = y;
        }
        __syncthreads();                             // scr/cmx reusable
    };

    for (; it < hi; ++it) {
        // ---- decode item -> (t, c) ----
        int g = (int)((65.0f - sqrtf((float)(4225 - 2*it))) * 0.5f);
        if (g < 0) g = 0; if (g > 31) g = 31;
        while (g > 0 && 2*g*(65 - g) > it) --g;
        while (2*(g+1)*(65 - (g+1)) <= it) ++g;
        int rem = it - 2*g*(65 - g);
        int ntc = 32 - g;
        int t  = 4*g + rem/ntc;
        int c  = rem - (rem/ntc)*ntc;
        int s0 = t + 4*c;

        // ---- t-change: flush, reset + scan-init carry ----
        if (t != cur_t) {                            // block-uniform branch
            if (cur_t >= 0) flush_t(cur_t);
            cur_t = t;
            rz0 = (f32x4){-1e30f,-1e30f,-1e30f,-1e30f};
            rz1 = rz0;
            #pragma unroll
            for (int i = 0; i < 8; ++i) mi[i] = (_Float16)(-65504.0f);
            for (int s = t; s < s0; ++s)             // nonempty only at block start
                mi = h8max(mi, *(const half8*)(pfb + s*DD));
        }

        // ---- stage cmx: fold 4 steps onto carried mi ----
        #pragma unroll
        for (int j = 0; j < 4; ++j) {
            int s = s0 + j; if (s > 127) s = 127;    // dup of valid s=127, same b
            mi = h8max(mi, *(const half8*)(pfb + s*DD));
            int row = j*32 + sb;
            *(half8*)(cmx + row*128 + ((dblk ^ (row & 15))*8)) = mi;
        }
        __syncthreads();                             // [A]

        // ---- L1': z1^T = W1a^T @ cmx^T, init = PW + b1, relu -> hS ----
        {
            const f32x4 bA1 = *(const f32x4*)(b1p + f0A + q*4);
            const f32x4 bB1 = *(const f32x4*)(b1p + f0B + q*4);
            f32x4 aA[4], aB[4], aC[4];
            #pragma unroll
            for (int rj = 0; rj < 4; ++rj) {
                int row = (rg*4 + rj)*16 + ln;           // j = row>>5, b = row&31
                int sj = s0 + (row >> 5);                // clamp s ONLY, preserve b
                if (sj > 127) sj = 127;
                int rowg = sj*32 + (row & 31);
                const _Float16* pwp = PW + (size_t)rowg*NP;
                half4 pA = *(const half4*)(pwp + f0A + q*4);
                half4 pB = *(const half4*)(pwp + f0B + q*4);
                aA[rj] = bA1; aB[rj] = bB1;
                #pragma unroll
                for (int i = 0; i < 4; ++i) { aA[rj][i] += (float)pA[i]; aB[rj][i] += (float)pB[i]; }
                if (has3) {
                    const f32x4 bC1 = *(const f32x4*)(b1p + f0C + q*4);
                    half4 pC = *(const half4*)(pwp + f0C + q*4);
                    aC[rj] = bC1;
                    #pragma unroll
                    for (int i = 0; i < 4; ++i) aC[rj][i] += (float)pC[i];
                }
            }
            #pragma unroll
            for (int kst = 0; kst < 4; ++kst) {
                half8 wA = *(const half8*)(W1tF + (f0A+ln)*256 + kst*32 + q*8);
                half8 wB = *(const half8*)(W1tF + (f0B+ln)*256 + kst*32 + q*8);
                half8 wC;
                if (has3) wC = *(const half8*)(W1tF + (f0C+ln)*256 + kst*32 + q*8);
                int kb = kst*4 + q;
                #pragma unroll
                for (int rj = 0; rj < 4; ++rj) {
                    int row = (rg*4 + rj)*16 + ln;
                    half8 bf = *(const half8*)(cmx + row*128 + ((kb ^ (row & 15))*8));
                    aA[rj] = MFMA(wA, bf, aA[rj]);
                    aB[rj] = MFMA(wB, bf, aB[rj]);
                    if (has3) aC[rj] = MFMA(wC, bf, aC[rj]);
                }
            }
            #pragma unroll
            for (int rj = 0; rj < 4; ++rj) {
                int row = (rg*4 + rj)*16 + ln;
                half4 hA, hB, hC;
                #pragma unroll
                for (int i = 0; i < 4; ++i) {
                    hA[i] = (_Float16)fmaxf(aA[rj][i], 0.f);
                    hB[i] = (_Float16)fmaxf(aB[rj][i], 0.f);
                }
                *(half4*)(hS + row*HSTR + f0A + q*4) = hA;
                *(half4*)(hS + row*HSTR + f0B + q*4) = hB;
                if (has3) {
                    #pragma unroll
                    for (int i = 0; i < 4; ++i) hC[i] = (_Float16)fmaxf(aC[rj][i], 0.f);
                    *(half4*)(hS + row*HSTR + f0C + q*4) = hC;
                }
            }
        }
        __syncthreads();                             // [B]

        // ---- L2': z2^T = W2^T @ h1^T, relu (held in regs until [C]) ----
        half4 h2A[4], h2B[4], h2C[4];
        {
            const f32x4 bA2 = *(const f32x4*)(b2p + f0A + q*4);
            const f32x4 bB2 = *(const f32x4*)(b2p + f0B + q*4);
            f32x4 aA[4], aB[4], aC[4];
            #pragma unroll
            for (int rj = 0; rj < 4; ++rj) {
                aA[rj] = bA2; aB[rj] = bB2;
                if (has3) aC[rj] = *(const f32x4*)(b2p + f0C + q*4);
            }
            #pragma unroll
            for (int kst = 0; kst < 5; ++kst) {
                half8 wA = *(const half8*)(W2t + (f0A+ln)*160 + kst*32 + q*8);
                half8 wB = *(const half8*)(W2t + (f0B+ln)*160 + kst*32 + q*8);
                half8 wC;
                if (has3) wC = *(const half8*)(W2t + (f0C+ln)*160 + kst*32 + q*8);
                #pragma unroll
                for (int rj = 0; rj < 4; ++rj) {
                    int row = (rg*4 + rj)*16 + ln;
                    half8 bf = *(const half8*)(hS + row*HSTR + kst*32 + q*8);
                    aA[rj] = MFMA(wA, bf, aA[rj]);
                    aB[rj] = MFMA(wB, bf, aB[rj]);
                    if (has3) aC[rj] = MFMA(wC, bf, aC[rj]);
                }
            }
            #pragma unroll
            for (int rj = 0; rj < 4; ++rj) {
                #pragma unroll
                for (int i = 0; i < 4; ++i) {
                    h2A[rj][i] = (_Float16)fmaxf(aA[rj][i], 0.f);
                    h2B[rj][i] = (_Float16)fmaxf(aB[rj][i], 0.f);
                    if (has3) h2C[rj][i] = (_Float16)fmaxf(aC[rj][i], 0.f);
                }
            }
        }
        __syncthreads();                             // [C] all h1 reads done
        #pragma unroll
        for (int rj = 0; rj < 4; ++rj) {
            int row = (rg*4 + rj)*16 + ln;
            *(half4*)(hS + row*HSTR + f0A + q*4) = h2A[rj];
            *(half4*)(hS + row*HSTR + f0B + q*4) = h2B[rj];
            if (has3) *(half4*)(hS + row*HSTR + f0C + q*4) = h2C[rj];
        }
        __syncthreads();                             // [D]

        // ---- L3': z3^T = W3^T @ h2^T; merge into register z-max ----
        {
            const f32x4 bz3 = *(const f32x4*)(b3 + og*16 + q*4);
            f32x4 z[4];
            #pragma unroll
            for (int rj = 0; rj < 4; ++rj) z[rj] = bz3;
            #pragma unroll
            for (int kst = 0; kst < 5; ++kst) {
                half8 wO = *(const half8*)(W3t + (og*16+ln)*160 + kst*32 + q*8);
                #pragma unroll
                for (int rj = 0; rj < 4; ++rj) {
                    int row = (rg3*4 + rj)*16 + ln;
                    half8 bf = *(const half8*)(hS + row*HSTR + kst*32 + q*8);
                    z[rj] = MFMA(wO, bf, z[rj]);
                }
            }
            // rows encode (j = rg3*2 + (rj>>1), b = (rj&1)*16 + ln); clamped
            // rows duplicate (s=127, same b) -> merge all unconditionally
            #pragma unroll
            for (int i = 0; i < 4; ++i) {
                rz0[i] = fmaxf(rz0[i], fmaxf(z[0][i], z[2][i]));
                rz1[i] = fmaxf(rz1[i], fmaxf(z[1][i], z[3][i]));
            }
        }
        __syncthreads();                             // protect hS/cmx for next item
    }

    if (cur_t >= 0) flush_t(cur_t);                  // final flush (+maybe finalize)
}

extern "C" void kernel_launch(void* const* d_in, const int* in_sizes, int n_in,
                              void* d_out, int out_size, void* d_ws, size_t ws_size,
                              hipStream_t stream) {
    const float* P  = (const float*)d_in[0];
    const float* W1 = (const float*)d_in[1];
    const float* b1 = (const float*)d_in[2];
    const float* W2 = (const float*)d_in[3];
    const float* b2 = (const float*)d_in[4];
    const float* W3 = (const float*)d_in[5];
    const float* b3 = (const float*)d_in[6];

    // zero the barrier + per-t arrival counters (ws is re-poisoned every call)
    hipMemsetAsync((char*)d_ws + CTR_OFF, 0, (128 + 2) * sizeof(unsigned), stream);

    hipFuncSetAttribute((const void*)tll_fused,
                        hipFuncAttributeMaxDynamicSharedMemorySize, 75776);
    tll_fused<<<NBLK, 512, 75776, stream>>>(P, W1, b1, W2, b2, W3, b3,
                                            (char*)d_ws, (float*)d_out);
}